// Round 1
// baseline (599.840 us; speedup 1.0000x reference)
//
#include <hip/hip_runtime.h>
#include <hip/hip_bf16.h>

#define EPS 1e-5f

// ---------------------------------------------------------------------------
// Block 1: conv 3->32, 5x5 pad2, on 32x32 -> BN -> ReLU -> AvgPool2 -> clip
// in  x   [1024][3][32][32]
// out     [1024][32][16][16]
// one block per image, 256 threads (one per pooled position), loop over oc.
// ---------------------------------------------------------------------------
__global__ __launch_bounds__(256, 2) void k_block1(
    const float* __restrict__ x, const float* __restrict__ w,
    const float* __restrict__ g, const float* __restrict__ b,
    const float* __restrict__ m, const float* __restrict__ v,
    float* __restrict__ out)
{
    __shared__ float xs[3][36][36];   // padded input (pad=2)
    __shared__ float wc[32][3][25];   // all weights: 9.6 KB
    __shared__ float sc[32], bi[32];
    const int img = blockIdx.x;
    const int t = threadIdx.x;

    for (int i = t; i < 3 * 36 * 36; i += 256) ((float*)xs)[i] = 0.f;
    __syncthreads();
    for (int i = t; i < 3 * 32 * 32; i += 256) {
        int ic = i >> 10, rem = i & 1023, yy = rem >> 5, xx = rem & 31;
        xs[ic][yy + 2][xx + 2] = x[img * 3072 + i];
    }
    for (int i = t; i < 32 * 75; i += 256) ((float*)wc)[i] = w[i];
    if (t < 32) {
        float s = g[t] * rsqrtf(v[t] + EPS);
        sc[t] = s; bi[t] = b[t] - m[t] * s;
    }
    __syncthreads();

    const int px = t & 15, py = t >> 4;
    const int r0 = 2 * py, c0 = 2 * px;

    for (int ocb = 0; ocb < 32; ocb += 8) {
        float acc[8][4];
        #pragma unroll
        for (int o = 0; o < 8; ++o)
            for (int q = 0; q < 4; ++q) acc[o][q] = 0.f;

        #pragma unroll
        for (int ic = 0; ic < 3; ++ic) {
            float p[6][6];
            #pragma unroll
            for (int r = 0; r < 6; ++r) {
                const float2 a0 = *(const float2*)&xs[ic][r0 + r][c0];
                const float2 a1 = *(const float2*)&xs[ic][r0 + r][c0 + 2];
                const float2 a2 = *(const float2*)&xs[ic][r0 + r][c0 + 4];
                p[r][0] = a0.x; p[r][1] = a0.y; p[r][2] = a1.x;
                p[r][3] = a1.y; p[r][4] = a2.x; p[r][5] = a2.y;
            }
            #pragma unroll
            for (int o = 0; o < 8; ++o) {
                const float* wp = wc[ocb + o][ic];
                #pragma unroll
                for (int ky = 0; ky < 5; ++ky)
                #pragma unroll
                for (int kx = 0; kx < 5; ++kx) {
                    float wv = wp[ky * 5 + kx];
                    acc[o][0] = fmaf(p[ky][kx],         wv, acc[o][0]);
                    acc[o][1] = fmaf(p[ky][kx + 1],     wv, acc[o][1]);
                    acc[o][2] = fmaf(p[ky + 1][kx],     wv, acc[o][2]);
                    acc[o][3] = fmaf(p[ky + 1][kx + 1], wv, acc[o][3]);
                }
            }
        }
        #pragma unroll
        for (int o = 0; o < 8; ++o) {
            int oc = ocb + o;
            float s = sc[oc], bb = bi[oc];
            float v0 = fmaxf(fmaf(acc[o][0], s, bb), 0.f);
            float v1 = fmaxf(fmaf(acc[o][1], s, bb), 0.f);
            float v2 = fmaxf(fmaf(acc[o][2], s, bb), 0.f);
            float v3 = fmaxf(fmaf(acc[o][3], s, bb), 0.f);
            float pv = 0.25f * (v0 + v1 + v2 + v3);
            pv = fminf(pv, 1.f);
            out[img * 8192 + oc * 256 + t] = pv;
        }
    }
}

// ---------------------------------------------------------------------------
// Block 2: conv 32->32, 5x5 pad2, on 16x16 -> BN -> ReLU -> pool -> clip
// in  [1024][32][16][16], out [1024][32][8][8]
// thread = (px 0..7, row-pair grp 0..3, oc-in-chunk 0..7); oc chunks of 8.
// ---------------------------------------------------------------------------
__global__ __launch_bounds__(256, 2) void k_block2(
    const float* __restrict__ xin, const float* __restrict__ w,
    const float* __restrict__ g, const float* __restrict__ b,
    const float* __restrict__ m, const float* __restrict__ v,
    float* __restrict__ out)
{
    __shared__ float xs[32][20][20];   // 51.2 KB padded input
    __shared__ float wc[8][32][25];    // 25.6 KB weight chunk
    __shared__ float sc[32], bi[32];
    const int img = blockIdx.x;
    const int t = threadIdx.x;

    for (int i = t; i < 32 * 20 * 20; i += 256) ((float*)xs)[i] = 0.f;
    __syncthreads();
    for (int i = t; i < 32 * 16 * 16; i += 256) {
        int ic = i >> 8, rem = i & 255, yy = rem >> 4, xx = rem & 15;
        xs[ic][yy + 2][xx + 2] = xin[img * 8192 + i];
    }
    if (t < 32) {
        float s = g[t] * rsqrtf(v[t] + EPS);
        sc[t] = s; bi[t] = b[t] - m[t] * s;
    }
    __syncthreads();

    const int px = t & 7, grp = (t >> 3) & 3, oco = t >> 5;
    const int c0 = 2 * px;   // patch col base (even -> float2 aligned)
    const int r0 = 4 * grp;  // patch row base: pooled rows {2g,2g+1} -> conv rows 4g..4g+3

    for (int ocb = 0; ocb < 32; ocb += 8) {
        for (int i = t; i < 8 * 32 * 25; i += 256) ((float*)wc)[i] = w[ocb * 800 + i];
        __syncthreads();
        const int oc = ocb + oco;
        float acc[2][4];
        #pragma unroll
        for (int q = 0; q < 2; ++q)
            for (int r = 0; r < 4; ++r) acc[q][r] = 0.f;

        for (int ic = 0; ic < 32; ++ic) {
            float p[8][6];
            #pragma unroll
            for (int r = 0; r < 8; ++r) {
                const float2 a0 = *(const float2*)&xs[ic][r0 + r][c0];
                const float2 a1 = *(const float2*)&xs[ic][r0 + r][c0 + 2];
                const float2 a2 = *(const float2*)&xs[ic][r0 + r][c0 + 4];
                p[r][0] = a0.x; p[r][1] = a0.y; p[r][2] = a1.x;
                p[r][3] = a1.y; p[r][4] = a2.x; p[r][5] = a2.y;
            }
            const float* wp = wc[oco][ic];
            #pragma unroll
            for (int ky = 0; ky < 5; ++ky)
            #pragma unroll
            for (int kx = 0; kx < 5; ++kx) {
                float wv = wp[ky * 5 + kx];
                acc[0][0] = fmaf(p[ky][kx],         wv, acc[0][0]);
                acc[0][1] = fmaf(p[ky][kx + 1],     wv, acc[0][1]);
                acc[0][2] = fmaf(p[ky + 1][kx],     wv, acc[0][2]);
                acc[0][3] = fmaf(p[ky + 1][kx + 1], wv, acc[0][3]);
                acc[1][0] = fmaf(p[ky + 2][kx],     wv, acc[1][0]);
                acc[1][1] = fmaf(p[ky + 2][kx + 1], wv, acc[1][1]);
                acc[1][2] = fmaf(p[ky + 3][kx],     wv, acc[1][2]);
                acc[1][3] = fmaf(p[ky + 3][kx + 1], wv, acc[1][3]);
            }
        }
        float s = sc[oc], bb = bi[oc];
        #pragma unroll
        for (int q = 0; q < 2; ++q) {
            float v0 = fmaxf(fmaf(acc[q][0], s, bb), 0.f);
            float v1 = fmaxf(fmaf(acc[q][1], s, bb), 0.f);
            float v2 = fmaxf(fmaf(acc[q][2], s, bb), 0.f);
            float v3 = fmaxf(fmaf(acc[q][3], s, bb), 0.f);
            float pv = 0.25f * (v0 + v1 + v2 + v3);
            pv = fminf(pv, 1.f);
            int pyy = 2 * grp + q;
            out[img * 2048 + oc * 64 + pyy * 8 + px] = pv;
        }
        __syncthreads();
    }
}

// ---------------------------------------------------------------------------
// Block 3: conv 32->64, 5x5 pad2, on 8x8 -> BN -> ReLU -> pool -> clip
// in  [1024][32][8][8], out [1024][64][4][4]
// thread = (px 0..3, py 0..3, oc-in-chunk 0..15); oc chunks of 16.
// ---------------------------------------------------------------------------
__global__ __launch_bounds__(256, 2) void k_block3(
    const float* __restrict__ xin, const float* __restrict__ w,
    const float* __restrict__ g, const float* __restrict__ b,
    const float* __restrict__ m, const float* __restrict__ v,
    float* __restrict__ out)
{
    __shared__ float xs[32][12][12];   // 18.4 KB padded input
    __shared__ float wc[16][32][25];   // 51.2 KB weight chunk
    __shared__ float sc[64], bi[64];
    const int img = blockIdx.x;
    const int t = threadIdx.x;

    for (int i = t; i < 32 * 12 * 12; i += 256) ((float*)xs)[i] = 0.f;
    __syncthreads();
    for (int i = t; i < 32 * 8 * 8; i += 256) {
        int ic = i >> 6, rem = i & 63, yy = rem >> 3, xx = rem & 7;
        xs[ic][yy + 2][xx + 2] = xin[img * 2048 + i];
    }
    if (t < 64) {
        float s = g[t] * rsqrtf(v[t] + EPS);
        sc[t] = s; bi[t] = b[t] - m[t] * s;
    }
    __syncthreads();

    const int px = t & 3, py = (t >> 2) & 3, oco = t >> 4;
    const int c0 = 2 * px, r0 = 2 * py;

    for (int ocb = 0; ocb < 64; ocb += 16) {
        for (int i = t; i < 16 * 32 * 25; i += 256) ((float*)wc)[i] = w[ocb * 800 + i];
        __syncthreads();
        const int oc = ocb + oco;
        float acc[4] = {0.f, 0.f, 0.f, 0.f};
        for (int ic = 0; ic < 32; ++ic) {
            float p[6][6];
            #pragma unroll
            for (int r = 0; r < 6; ++r) {
                const float2 a0 = *(const float2*)&xs[ic][r0 + r][c0];
                const float2 a1 = *(const float2*)&xs[ic][r0 + r][c0 + 2];
                const float2 a2 = *(const float2*)&xs[ic][r0 + r][c0 + 4];
                p[r][0] = a0.x; p[r][1] = a0.y; p[r][2] = a1.x;
                p[r][3] = a1.y; p[r][4] = a2.x; p[r][5] = a2.y;
            }
            const float* wp = wc[oco][ic];
            #pragma unroll
            for (int ky = 0; ky < 5; ++ky)
            #pragma unroll
            for (int kx = 0; kx < 5; ++kx) {
                float wv = wp[ky * 5 + kx];
                acc[0] = fmaf(p[ky][kx],         wv, acc[0]);
                acc[1] = fmaf(p[ky][kx + 1],     wv, acc[1]);
                acc[2] = fmaf(p[ky + 1][kx],     wv, acc[2]);
                acc[3] = fmaf(p[ky + 1][kx + 1], wv, acc[3]);
            }
        }
        float s = sc[oc], bb = bi[oc];
        float v0 = fmaxf(fmaf(acc[0], s, bb), 0.f);
        float v1 = fmaxf(fmaf(acc[1], s, bb), 0.f);
        float v2 = fmaxf(fmaf(acc[2], s, bb), 0.f);
        float v3 = fmaxf(fmaf(acc[3], s, bb), 0.f);
        float pv = 0.25f * (v0 + v1 + v2 + v3);
        pv = fminf(pv, 1.f);
        out[img * 1024 + oc * 16 + py * 4 + px] = pv;
        __syncthreads();
    }
}

// ---------------------------------------------------------------------------
// Final: 4x4 valid conv 64->10 (i.e. [1024,1024]x[1024,10] dot) + BN1d affine
// in [1024][64][4][4] (=1024 floats/img), w4 [10][1024], out [1024][10]
// ---------------------------------------------------------------------------
__global__ void k_final(const float* __restrict__ xin, const float* __restrict__ w,
                        const float* __restrict__ g, const float* __restrict__ b,
                        const float* __restrict__ m, const float* __restrict__ v,
                        float* __restrict__ out)
{
    int idx = blockIdx.x * 256 + threadIdx.x;
    if (idx >= 1024 * 10) return;
    int bimg = idx / 10, oc = idx % 10;
    const float4* xp = (const float4*)(xin + bimg * 1024);
    const float4* wp = (const float4*)(w + oc * 1024);
    float acc = 0.f;
    for (int k = 0; k < 256; ++k) {
        float4 a = xp[k], ww = wp[k];
        acc = fmaf(a.x, ww.x, acc);
        acc = fmaf(a.y, ww.y, acc);
        acc = fmaf(a.z, ww.z, acc);
        acc = fmaf(a.w, ww.w, acc);
    }
    float s = g[oc] * rsqrtf(v[oc] + EPS);
    out[idx] = acc * s + (b[oc] - m[oc] * s);
}

extern "C" void kernel_launch(void* const* d_in, const int* in_sizes, int n_in,
                              void* d_out, int out_size, void* d_ws, size_t ws_size,
                              hipStream_t stream) {
    const float* x  = (const float*)d_in[0];
    const float* w1 = (const float*)d_in[1];
    const float* g1 = (const float*)d_in[2];
    const float* b1 = (const float*)d_in[3];
    const float* m1 = (const float*)d_in[4];
    const float* v1 = (const float*)d_in[5];
    const float* w2 = (const float*)d_in[6];
    const float* g2 = (const float*)d_in[7];
    const float* b2 = (const float*)d_in[8];
    const float* m2 = (const float*)d_in[9];
    const float* v2 = (const float*)d_in[10];
    const float* w3 = (const float*)d_in[11];
    const float* g3 = (const float*)d_in[12];
    const float* b3 = (const float*)d_in[13];
    const float* m3 = (const float*)d_in[14];
    const float* v3 = (const float*)d_in[15];
    const float* w4 = (const float*)d_in[16];
    const float* g4 = (const float*)d_in[17];
    const float* b4 = (const float*)d_in[18];
    const float* m4 = (const float*)d_in[19];
    const float* v4 = (const float*)d_in[20];
    float* out = (float*)d_out;

    float* buf1 = (float*)d_ws;              // [1024][32][16][16] = 33.55 MB
    float* buf2 = buf1 + 1024 * 32 * 16 * 16; // [1024][32][8][8]  =  8.39 MB
    float* buf3 = buf2 + 1024 * 32 * 8 * 8;   // [1024][64][4][4]  =  4.19 MB

    k_block1<<<1024, 256, 0, stream>>>(x, w1, g1, b1, m1, v1, buf1);
    k_block2<<<1024, 256, 0, stream>>>(buf1, w2, g2, b2, m2, v2, buf2);
    k_block3<<<1024, 256, 0, stream>>>(buf2, w3, g3, b3, m3, v3, buf3);
    k_final<<<40, 256, 0, stream>>>(buf3, w4, g4, b4, m4, v4, out);
}

// Round 2
// 158.627 us; speedup vs baseline: 3.7814x; 3.7814x over previous
//
#include <hip/hip_runtime.h>
#include <hip/hip_bf16.h>

#define EPS 1e-5f

typedef __bf16 v8bf __attribute__((ext_vector_type(8)));
typedef float  v4f  __attribute__((ext_vector_type(4)));

// ---------------------------------------------------------------------------
// Weight transform: build per-tap MFMA B-fragments for conv2 and conv3.
// fb2: [tap(25)][nt(2)][lane(64)][8] bf16   (B[k=ic][n=oc] frag, 16x16x32)
// fb3: [tap(25)][nt(4)][lane(64)][8] bf16
// B-frag element: lane l, reg j -> B[k=(l>>4)*8+j][n=l&15] = w[oc][ic][ky][kx]
// ---------------------------------------------------------------------------
__global__ void k_wtrans(const float* __restrict__ w2, const float* __restrict__ w3,
                         __hip_bfloat16* __restrict__ fb2, __hip_bfloat16* __restrict__ fb3)
{
    int idx = blockIdx.x * 256 + threadIdx.x;
    if (idx < 25 * 2 * 64) {
        int lane = idx & 63, fi = idx >> 6;      // fi = tap*2 + nt
        int tap = fi >> 1, nt = fi & 1;
        int oc = nt * 16 + (lane & 15), ic0 = (lane >> 4) * 8;
        __hip_bfloat16* dst = fb2 + idx * 8;
        #pragma unroll
        for (int j = 0; j < 8; ++j)
            dst[j] = __float2bfloat16(w2[oc * 800 + (ic0 + j) * 25 + tap]);
    } else if (idx < 25 * 2 * 64 + 25 * 4 * 64) {
        int k = idx - 25 * 2 * 64;
        int lane = k & 63, fi = k >> 6;          // fi = tap*4 + nt
        int tap = fi >> 2, nt = fi & 3;
        int oc = nt * 16 + (lane & 15), ic0 = (lane >> 4) * 8;
        __hip_bfloat16* dst = fb3 + k * 8;
        #pragma unroll
        for (int j = 0; j < 8; ++j)
            dst[j] = __float2bfloat16(w3[oc * 800 + (ic0 + j) * 25 + tap]);
    }
}

// ---------------------------------------------------------------------------
// Block 1: conv 3->32 (5x5 pad2, 32x32) -> BN -> ReLU -> pool -> clip. fp32.
// Output written as bf16 in [img][pix(16x16)][oc(32)] layout for block2's LDS.
// ---------------------------------------------------------------------------
__global__ __launch_bounds__(256, 2) void k_block1(
    const float* __restrict__ x, const float* __restrict__ w,
    const float* __restrict__ g, const float* __restrict__ b,
    const float* __restrict__ m, const float* __restrict__ v,
    __hip_bfloat16* __restrict__ out)
{
    __shared__ float xs[3][36][36];
    __shared__ float wc[32][3][28];   // tap dim padded 25->28 for float4 loads
    __shared__ float sc[32], bi[32];
    const int img = blockIdx.x;
    const int t = threadIdx.x;

    for (int i = t; i < 3 * 36 * 36; i += 256) ((float*)xs)[i] = 0.f;
    __syncthreads();
    for (int i = t; i < 3 * 32 * 32; i += 256) {
        int ic = i >> 10, rem = i & 1023, yy = rem >> 5, xx = rem & 31;
        xs[ic][yy + 2][xx + 2] = x[img * 3072 + i];
    }
    for (int i = t; i < 2400; i += 256) {
        int oc = i / 75, rem = i % 75, ic = rem / 25, tap = rem % 25;
        wc[oc][ic][tap] = w[i];
    }
    if (t < 32) {
        float s = g[t] * rsqrtf(v[t] + EPS);
        sc[t] = s; bi[t] = b[t] - m[t] * s;
    }
    __syncthreads();

    const int px = t & 15, py = t >> 4;
    const int r0 = 2 * py, c0 = 2 * px;

    for (int ocb = 0; ocb < 32; ocb += 8) {
        float acc[8][4];
        #pragma unroll
        for (int o = 0; o < 8; ++o)
            #pragma unroll
            for (int q = 0; q < 4; ++q) acc[o][q] = 0.f;

        #pragma unroll
        for (int ic = 0; ic < 3; ++ic) {
            float p[6][6];
            #pragma unroll
            for (int r = 0; r < 6; ++r) {
                const float2 a0 = *(const float2*)&xs[ic][r0 + r][c0];
                const float2 a1 = *(const float2*)&xs[ic][r0 + r][c0 + 2];
                const float2 a2 = *(const float2*)&xs[ic][r0 + r][c0 + 4];
                p[r][0] = a0.x; p[r][1] = a0.y; p[r][2] = a1.x;
                p[r][3] = a1.y; p[r][4] = a2.x; p[r][5] = a2.y;
            }
            #pragma unroll
            for (int o = 0; o < 8; ++o) {
                const float* wp = wc[ocb + o][ic];
                alignas(16) float wr[28];
                #pragma unroll
                for (int q = 0; q < 7; ++q)
                    *(float4*)&wr[q * 4] = *(const float4*)&wp[q * 4];
                #pragma unroll
                for (int tap = 0; tap < 25; ++tap) {
                    const int ky = tap / 5, kx = tap % 5;
                    const float wv = wr[tap];
                    acc[o][0] = fmaf(p[ky][kx],         wv, acc[o][0]);
                    acc[o][1] = fmaf(p[ky][kx + 1],     wv, acc[o][1]);
                    acc[o][2] = fmaf(p[ky + 1][kx],     wv, acc[o][2]);
                    acc[o][3] = fmaf(p[ky + 1][kx + 1], wv, acc[o][3]);
                }
            }
        }
        alignas(16) __hip_bfloat16 ob[8];
        #pragma unroll
        for (int o = 0; o < 8; ++o) {
            int oc = ocb + o;
            float s = sc[oc], bb = bi[oc];
            float v0 = fmaxf(fmaf(acc[o][0], s, bb), 0.f);
            float v1 = fmaxf(fmaf(acc[o][1], s, bb), 0.f);
            float v2 = fmaxf(fmaf(acc[o][2], s, bb), 0.f);
            float v3 = fmaxf(fmaf(acc[o][3], s, bb), 0.f);
            float pv = fminf(0.25f * (v0 + v1 + v2 + v3), 1.f);
            ob[o] = __float2bfloat16(pv);
        }
        *(uint4*)(out + (size_t)(img * 256 + t) * 32 + ocb) = *(const uint4*)ob;
    }
}

// ---------------------------------------------------------------------------
// Block 2 (MFMA): conv 32->32 (5x5 pad2, 16x16) -> BN -> ReLU -> pool -> clip
// in  [img][256 pix][32 ic] bf16, out [img][64 pix][32 oc] bf16
// Tap decomposition: 25 taps x (M=16 x-positions, N=16 oc, K=32 ic) MFMAs.
// 4 waves; wave handles conv row-pairs {w, w+4} (pooled rows).
// ---------------------------------------------------------------------------
__global__ __launch_bounds__(256, 4) void k_block2(
    const __hip_bfloat16* __restrict__ xin, const __hip_bfloat16* __restrict__ fb,
    const float* __restrict__ g, const float* __restrict__ b,
    const float* __restrict__ m, const float* __restrict__ v,
    __hip_bfloat16* __restrict__ out)
{
    __shared__ __hip_bfloat16 xs[20][20][32];   // [ypad][xpad][ic] 25.6 KB
    __shared__ float sc[32], bi[32];
    const int img = blockIdx.x, t = threadIdx.x;

    for (int i = t; i < 1600; i += 256) ((uint4*)xs)[i] = make_uint4(0, 0, 0, 0);
    if (t < 32) {
        float s = g[t] * rsqrtf(v[t] + EPS);
        sc[t] = s; bi[t] = b[t] - m[t] * s;
    }
    __syncthreads();
    for (int i = t; i < 1024; i += 256) {   // 256 pix * 4 chunks of 8 ic
        uint4 val = *(const uint4*)(xin + (size_t)img * 8192 + i * 8);
        int pix = i >> 2, grp = i & 3;
        *(uint4*)&xs[(pix >> 4) + 2][(pix & 15) + 2][grp * 8] = val;
    }
    __syncthreads();

    const int lane = t & 63, wave = t >> 6;
    const int lo = lane & 15, hi = lane >> 4;

    for (int rpi = 0; rpi < 2; ++rpi) {
        const int rp = wave + rpi * 4;        // pooled row 0..7
        const int y0 = rp * 2, y1 = y0 + 1;   // conv rows
        v4f a00 = {0.f, 0.f, 0.f, 0.f}, a01 = {0.f, 0.f, 0.f, 0.f};
        v4f a10 = {0.f, 0.f, 0.f, 0.f}, a11 = {0.f, 0.f, 0.f, 0.f};
        #pragma unroll
        for (int tap = 0; tap < 25; ++tap) {
            const int ky = tap / 5, kx = tap % 5;
            v8bf bf0 = *(const v8bf*)(fb + (tap * 2 + 0) * 512 + lane * 8);
            v8bf bf1 = *(const v8bf*)(fb + (tap * 2 + 1) * 512 + lane * 8);
            v8bf av0 = *(const v8bf*)&xs[y0 + ky][lo + kx][hi * 8];
            v8bf av1 = *(const v8bf*)&xs[y1 + ky][lo + kx][hi * 8];
            a00 = __builtin_amdgcn_mfma_f32_16x16x32_bf16(av0, bf0, a00, 0, 0, 0);
            a01 = __builtin_amdgcn_mfma_f32_16x16x32_bf16(av0, bf1, a01, 0, 0, 0);
            a10 = __builtin_amdgcn_mfma_f32_16x16x32_bf16(av1, bf0, a10, 0, 0, 0);
            a11 = __builtin_amdgcn_mfma_f32_16x16x32_bf16(av1, bf1, a11, 0, 0, 0);
        }
        // lane holds x = hi*4 + r (r=0..3), oc = nt*16 + lo
        #define EPI2(AY0, AY1, NT) { \
            const int oc = (NT) * 16 + lo; \
            const float s = sc[oc], bb = bi[oc]; \
            float u0 = fmaxf(fmaf((AY0)[0], s, bb), 0.f); \
            float u1 = fmaxf(fmaf((AY0)[1], s, bb), 0.f); \
            float u2 = fmaxf(fmaf((AY0)[2], s, bb), 0.f); \
            float u3 = fmaxf(fmaf((AY0)[3], s, bb), 0.f); \
            float q0 = fmaxf(fmaf((AY1)[0], s, bb), 0.f); \
            float q1 = fmaxf(fmaf((AY1)[1], s, bb), 0.f); \
            float q2 = fmaxf(fmaf((AY1)[2], s, bb), 0.f); \
            float q3 = fmaxf(fmaf((AY1)[3], s, bb), 0.f); \
            float p0 = fminf(0.25f * (u0 + u1 + q0 + q1), 1.f); \
            float p1 = fminf(0.25f * (u2 + u3 + q2 + q3), 1.f); \
            size_t base = (size_t)img * 2048 + (rp * 8 + hi * 2) * 32 + oc; \
            out[base]      = __float2bfloat16(p0); \
            out[base + 32] = __float2bfloat16(p1); }
        EPI2(a00, a10, 0)
        EPI2(a01, a11, 1)
        #undef EPI2
    }
}

// ---------------------------------------------------------------------------
// Block 3 (MFMA): conv 32->64 (5x5 pad2, 8x8) -> BN -> ReLU -> pool -> clip
// in [img][64 pix][32 ic] bf16, out [img][64 oc][4][4] f32
// wave w owns M-tile w = positions 16w..16w+15 (conv rows 2w, 2w+1).
// ---------------------------------------------------------------------------
__global__ __launch_bounds__(256, 4) void k_block3(
    const __hip_bfloat16* __restrict__ xin, const __hip_bfloat16* __restrict__ fb,
    const float* __restrict__ g, const float* __restrict__ b,
    const float* __restrict__ m, const float* __restrict__ v,
    float* __restrict__ out)
{
    __shared__ __hip_bfloat16 xs[12][12][32];   // 9.2 KB
    __shared__ float sc[64], bi[64];
    const int img = blockIdx.x, t = threadIdx.x;

    for (int i = t; i < 576; i += 256) ((uint4*)xs)[i] = make_uint4(0, 0, 0, 0);
    if (t < 64) {
        float s = g[t] * rsqrtf(v[t] + EPS);
        sc[t] = s; bi[t] = b[t] - m[t] * s;
    }
    __syncthreads();
    if (t < 256) {
        uint4 val = *(const uint4*)(xin + (size_t)img * 2048 + t * 8);
        int pix = t >> 2, grp = t & 3;
        *(uint4*)&xs[(pix >> 3) + 2][(pix & 7) + 2][grp * 8] = val;
    }
    __syncthreads();

    const int lane = t & 63, w = t >> 6;
    const int lo = lane & 15, hi = lane >> 4;
    const int ya = 2 * w + (lo >> 3), xa = lo & 7;   // A-operand position

    v4f ac0 = {0.f,0.f,0.f,0.f}, ac1 = {0.f,0.f,0.f,0.f};
    v4f ac2 = {0.f,0.f,0.f,0.f}, ac3 = {0.f,0.f,0.f,0.f};
    #pragma unroll
    for (int tap = 0; tap < 25; ++tap) {
        const int ky = tap / 5, kx = tap % 5;
        v8bf av = *(const v8bf*)&xs[ya + ky][xa + kx][hi * 8];
        v8bf b0 = *(const v8bf*)(fb + (tap * 4 + 0) * 512 + lane * 8);
        v8bf b1 = *(const v8bf*)(fb + (tap * 4 + 1) * 512 + lane * 8);
        v8bf b2 = *(const v8bf*)(fb + (tap * 4 + 2) * 512 + lane * 8);
        v8bf b3 = *(const v8bf*)(fb + (tap * 4 + 3) * 512 + lane * 8);
        ac0 = __builtin_amdgcn_mfma_f32_16x16x32_bf16(av, b0, ac0, 0, 0, 0);
        ac1 = __builtin_amdgcn_mfma_f32_16x16x32_bf16(av, b1, ac1, 0, 0, 0);
        ac2 = __builtin_amdgcn_mfma_f32_16x16x32_bf16(av, b2, ac2, 0, 0, 0);
        ac3 = __builtin_amdgcn_mfma_f32_16x16x32_bf16(av, b3, ac3, 0, 0, 0);
    }
    // lane holds pos = 16w + hi*4 + r -> y = 2w + (hi>>1), x = (hi&1)*4 + r
    const int xb = (hi & 1) * 2;   // pooled-x base
    #define EPI3(AC, NT) { \
        const int oc = (NT) * 16 + lo; \
        const float s = sc[oc], bb = bi[oc]; \
        float v0 = fmaxf(fmaf((AC)[0], s, bb), 0.f); \
        float v1 = fmaxf(fmaf((AC)[1], s, bb), 0.f); \
        float v2 = fmaxf(fmaf((AC)[2], s, bb), 0.f); \
        float v3 = fmaxf(fmaf((AC)[3], s, bb), 0.f); \
        float s01 = v0 + v1, s23 = v2 + v3; \
        float o01 = __shfl_xor(s01, 32); \
        float o23 = __shfl_xor(s23, 32); \
        float p0 = fminf(0.25f * (s01 + o01), 1.f); \
        float p1 = fminf(0.25f * (s23 + o23), 1.f); \
        if (hi < 2) { \
            size_t base = (size_t)img * 1024 + oc * 16 + w * 4 + xb; \
            out[base] = p0; out[base + 1] = p1; } }
    EPI3(ac0, 0)
    EPI3(ac1, 1)
    EPI3(ac2, 2)
    EPI3(ac3, 3)
    #undef EPI3
}

// ---------------------------------------------------------------------------
// Final: [1024,1024]x[1024,10] + BN1d affine
// ---------------------------------------------------------------------------
__global__ void k_final(const float* __restrict__ xin, const float* __restrict__ w,
                        const float* __restrict__ g, const float* __restrict__ b,
                        const float* __restrict__ m, const float* __restrict__ v,
                        float* __restrict__ out)
{
    int idx = blockIdx.x * 256 + threadIdx.x;
    if (idx >= 1024 * 10) return;
    int bimg = idx / 10, oc = idx % 10;
    const float4* xp = (const float4*)(xin + bimg * 1024);
    const float4* wp = (const float4*)(w + oc * 1024);
    float acc = 0.f;
    for (int k = 0; k < 256; ++k) {
        float4 a = xp[k], ww = wp[k];
        acc = fmaf(a.x, ww.x, acc);
        acc = fmaf(a.y, ww.y, acc);
        acc = fmaf(a.z, ww.z, acc);
        acc = fmaf(a.w, ww.w, acc);
    }
    float s = g[oc] * rsqrtf(v[oc] + EPS);
    out[idx] = acc * s + (b[oc] - m[oc] * s);
}

extern "C" void kernel_launch(void* const* d_in, const int* in_sizes, int n_in,
                              void* d_out, int out_size, void* d_ws, size_t ws_size,
                              hipStream_t stream) {
    const float* x  = (const float*)d_in[0];
    const float* w1 = (const float*)d_in[1];
    const float* g1 = (const float*)d_in[2];
    const float* b1 = (const float*)d_in[3];
    const float* m1 = (const float*)d_in[4];
    const float* v1 = (const float*)d_in[5];
    const float* w2 = (const float*)d_in[6];
    const float* g2 = (const float*)d_in[7];
    const float* b2 = (const float*)d_in[8];
    const float* m2 = (const float*)d_in[9];
    const float* v2 = (const float*)d_in[10];
    const float* w3 = (const float*)d_in[11];
    const float* g3 = (const float*)d_in[12];
    const float* b3 = (const float*)d_in[13];
    const float* m3 = (const float*)d_in[14];
    const float* v3 = (const float*)d_in[15];
    const float* w4 = (const float*)d_in[16];
    const float* g4 = (const float*)d_in[17];
    const float* b4 = (const float*)d_in[18];
    const float* m4 = (const float*)d_in[19];
    const float* v4 = (const float*)d_in[20];
    float* out = (float*)d_out;

    char* base = (char*)d_ws;
    __hip_bfloat16* buf1 = (__hip_bfloat16*)base;                    // 16.78 MB [1024][256][32]
    __hip_bfloat16* buf2 = (__hip_bfloat16*)(base + 16777216);       //  4.19 MB [1024][64][32]
    float*          buf3 = (float*)(base + 20971520);                //  4.19 MB [1024][64][16]
    __hip_bfloat16* fb2  = (__hip_bfloat16*)(base + 25165824);       //  51.2 KB
    __hip_bfloat16* fb3  = (__hip_bfloat16*)(base + 25165824 + 65536); // 102.4 KB

    k_wtrans<<<38, 256, 0, stream>>>(w2, w3, fb2, fb3);
    k_block1<<<1024, 256, 0, stream>>>(x, w1, g1, b1, m1, v1, buf1);
    k_block2<<<1024, 256, 0, stream>>>(buf1, fb2, g2, b2, m2, v2, buf2);
    k_block3<<<1024, 256, 0, stream>>>(buf2, fb3, g3, b3, m3, v3, buf3);
    k_final<<<40, 256, 0, stream>>>(buf3, w4, g4, b4, m4, v4, out);
}

// Round 3
// 59.294 us; speedup vs baseline: 10.1164x; 2.6753x over previous
//
#include <hip/hip_runtime.h>
#include <hip/hip_bf16.h>

#define EPS 1e-5f

typedef __bf16 v8bf __attribute__((ext_vector_type(8)));
typedef __bf16 v4bf __attribute__((ext_vector_type(4)));
typedef float  v4f  __attribute__((ext_vector_type(4)));

// ---------------------------------------------------------------------------
// Weight transform: per-tap MFMA B-fragments.
// fb1: [ky(5)][nt(2)][lane(64)][8]  k=(dx,ic): dx=k>>2 (0..7), ic=k&3; zero pad
// fb2: [tap(25)][nt(2)][lane(64)][8]  k = ic (0..31)
// fb3: [tap(25)][nt(4)][lane(64)][8]  k = ic (0..31)
// B elem: lane l, reg j -> B[k=(l>>4)*8+j][n=l&15]
// ---------------------------------------------------------------------------
__global__ void k_wtrans(const float* __restrict__ w1, const float* __restrict__ w2,
                         const float* __restrict__ w3,
                         __hip_bfloat16* __restrict__ fb1, __hip_bfloat16* __restrict__ fb2,
                         __hip_bfloat16* __restrict__ fb3)
{
    int idx = blockIdx.x * 256 + threadIdx.x;
    if (idx < 640) {                               // fb1: 5*2*64
        int lane = idx & 63, fi = idx >> 6;        // fi = ky*2 + nt
        int ky = fi >> 1, nt = fi & 1;
        int oc = nt * 16 + (lane & 15), k0 = (lane >> 4) * 8;
        __hip_bfloat16* dst = fb1 + idx * 8;
        #pragma unroll
        for (int j = 0; j < 8; ++j) {
            int k = k0 + j, dx = k >> 2, ic = k & 3;
            float val = (dx < 5 && ic < 3) ? w1[oc * 75 + ic * 25 + ky * 5 + dx] : 0.f;
            dst[j] = __float2bfloat16(val);
        }
    } else if (idx < 640 + 3200) {                 // fb2: 25*2*64
        int k2 = idx - 640;
        int lane = k2 & 63, fi = k2 >> 6;          // fi = tap*2 + nt
        int tap = fi >> 1, nt = fi & 1;
        int oc = nt * 16 + (lane & 15), ic0 = (lane >> 4) * 8;
        __hip_bfloat16* dst = fb2 + k2 * 8;
        #pragma unroll
        for (int j = 0; j < 8; ++j)
            dst[j] = __float2bfloat16(w2[oc * 800 + (ic0 + j) * 25 + tap]);
    } else if (idx < 640 + 3200 + 6400) {          // fb3: 25*4*64
        int k3 = idx - 3840;
        int lane = k3 & 63, fi = k3 >> 6;          // fi = tap*4 + nt
        int tap = fi >> 2, nt = fi & 3;
        int oc = nt * 16 + (lane & 15), ic0 = (lane >> 4) * 8;
        __hip_bfloat16* dst = fb3 + k3 * 8;
        #pragma unroll
        for (int j = 0; j < 8; ++j)
            dst[j] = __float2bfloat16(w3[oc * 800 + (ic0 + j) * 25 + tap]);
    }
}

// ---------------------------------------------------------------------------
// Block 1 (MFMA): conv 3->32 (5x5 pad2, 32x32) -> BN -> ReLU -> pool -> clip
// K-packing k=(dx,ic): A[row=x][k] = xs[y+ky][x + dx][ic]  (zero-pad dx>4,ic=3)
// xs layout [yy 37][xx 40][ic 4] bf16 -> A-frag = 16 contiguous bytes/lane.
// wave handles pooled rows {w, w+4, w+8, w+12}; M-tile = 16 x-positions.
// out: [img][pix 16x16][oc 32] bf16 (block2's staging layout)
// ---------------------------------------------------------------------------
__global__ __launch_bounds__(256, 2) void k_block1(
    const float* __restrict__ x, const __hip_bfloat16* __restrict__ fb,
    const float* __restrict__ g, const float* __restrict__ b,
    const float* __restrict__ m, const float* __restrict__ v,
    __hip_bfloat16* __restrict__ out)
{
    __shared__ __hip_bfloat16 xs[37][40][4];   // 11.84 KB
    __shared__ float sc[32], bi[32];
    const int img = blockIdx.x, t = threadIdx.x;

    for (int i = t; i < 740; i += 256) ((uint4*)xs)[i] = make_uint4(0, 0, 0, 0);
    if (t < 32) {
        float s = g[t] * rsqrtf(v[t] + EPS);
        sc[t] = s; bi[t] = b[t] - m[t] * s;
    }
    __syncthreads();
    #pragma unroll
    for (int it = 0; it < 3; ++it) {
        int i = t + it * 256;                  // 768 float4 total
        float4 val = *(const float4*)(x + img * 3072 + i * 4);
        int ic = i >> 8, rem = i & 255;
        int y = rem >> 3, xx = (rem & 7) * 4;
        xs[y + 2][xx + 2][ic]     = __float2bfloat16(val.x);
        xs[y + 2][xx + 3][ic]     = __float2bfloat16(val.y);
        xs[y + 2][xx + 4][ic]     = __float2bfloat16(val.z);
        xs[y + 2][xx + 5][ic]     = __float2bfloat16(val.w);
    }
    __syncthreads();

    const int lane = t & 63, wave = t >> 6;
    const int lo = lane & 15, hi = lane >> 4;

    v8bf bw[5][2];
    #pragma unroll
    for (int ky = 0; ky < 5; ++ky)
        #pragma unroll
        for (int nt = 0; nt < 2; ++nt)
            bw[ky][nt] = *(const v8bf*)(fb + ((ky * 2 + nt) * 64 + lane) * 8);

    #pragma unroll
    for (int pi = 0; pi < 4; ++pi) {
        const int pr = wave + pi * 4;          // pooled row 0..15
        const int y0 = 2 * pr;                 // conv row base (= padded row base)
        v4f acc[2][2][2];                      // [yb][xh][nt]
        #pragma unroll
        for (int a0 = 0; a0 < 2; ++a0)
            #pragma unroll
            for (int a1 = 0; a1 < 2; ++a1)
                #pragma unroll
                for (int a2 = 0; a2 < 2; ++a2)
                    acc[a0][a1][a2] = (v4f){0.f, 0.f, 0.f, 0.f};

        #pragma unroll
        for (int xh = 0; xh < 2; ++xh) {
            const int xx = xh * 16 + lo + hi * 2;
            v8bf av[6];
            #pragma unroll
            for (int r = 0; r < 6; ++r) {
                v4bf lo4 = *(const v4bf*)&xs[y0 + r][xx][0];
                v4bf hi4 = *(const v4bf*)&xs[y0 + r][xx + 1][0];
                av[r] = __builtin_shufflevector(lo4, hi4, 0, 1, 2, 3, 4, 5, 6, 7);
            }
            #pragma unroll
            for (int ky = 0; ky < 5; ++ky) {
                acc[0][xh][0] = __builtin_amdgcn_mfma_f32_16x16x32_bf16(av[ky],     bw[ky][0], acc[0][xh][0], 0, 0, 0);
                acc[0][xh][1] = __builtin_amdgcn_mfma_f32_16x16x32_bf16(av[ky],     bw[ky][1], acc[0][xh][1], 0, 0, 0);
                acc[1][xh][0] = __builtin_amdgcn_mfma_f32_16x16x32_bf16(av[ky + 1], bw[ky][0], acc[1][xh][0], 0, 0, 0);
                acc[1][xh][1] = __builtin_amdgcn_mfma_f32_16x16x32_bf16(av[ky + 1], bw[ky][1], acc[1][xh][1], 0, 0, 0);
            }
        }
        // lane: D row = x-in-tile = hi*4+reg, D col = oc_lo = lo
        #pragma unroll
        for (int xh = 0; xh < 2; ++xh)
            #pragma unroll
            for (int nt = 0; nt < 2; ++nt) {
                const int oc = nt * 16 + lo;
                const float s = sc[oc], bb = bi[oc];
                float u0 = fmaxf(fmaf(acc[0][xh][nt][0], s, bb), 0.f);
                float u1 = fmaxf(fmaf(acc[0][xh][nt][1], s, bb), 0.f);
                float u2 = fmaxf(fmaf(acc[0][xh][nt][2], s, bb), 0.f);
                float u3 = fmaxf(fmaf(acc[0][xh][nt][3], s, bb), 0.f);
                float q0 = fmaxf(fmaf(acc[1][xh][nt][0], s, bb), 0.f);
                float q1 = fmaxf(fmaf(acc[1][xh][nt][1], s, bb), 0.f);
                float q2 = fmaxf(fmaf(acc[1][xh][nt][2], s, bb), 0.f);
                float q3 = fmaxf(fmaf(acc[1][xh][nt][3], s, bb), 0.f);
                float p0 = fminf(0.25f * (u0 + u1 + q0 + q1), 1.f);
                float p1 = fminf(0.25f * (u2 + u3 + q2 + q3), 1.f);
                size_t base = (size_t)(img * 256 + pr * 16 + xh * 8 + hi * 2) * 32 + oc;
                out[base]      = __float2bfloat16(p0);
                out[base + 32] = __float2bfloat16(p1);
            }
    }
}

// ---------------------------------------------------------------------------
// Block 2 (MFMA): conv 32->32 (5x5 pad2, 16x16) -> BN -> ReLU -> pool -> clip
// kx-outer: B-frags hoisted (50 global loads/lane, was 100); A-frag shared
// across y-pair (av[ky], av[ky+1]). ic dim padded 32->40 (bank conflicts).
// ---------------------------------------------------------------------------
__global__ __launch_bounds__(256, 2) void k_block2(
    const __hip_bfloat16* __restrict__ xin, const __hip_bfloat16* __restrict__ fb,
    const float* __restrict__ g, const float* __restrict__ b,
    const float* __restrict__ m, const float* __restrict__ v,
    __hip_bfloat16* __restrict__ out)
{
    __shared__ __hip_bfloat16 xs[20][20][40];   // 32 KB
    __shared__ float sc[32], bi[32];
    const int img = blockIdx.x, t = threadIdx.x;

    for (int i = t; i < 2000; i += 256) ((uint4*)xs)[i] = make_uint4(0, 0, 0, 0);
    if (t < 32) {
        float s = g[t] * rsqrtf(v[t] + EPS);
        sc[t] = s; bi[t] = b[t] - m[t] * s;
    }
    __syncthreads();
    for (int i = t; i < 1024; i += 256) {
        uint4 val = *(const uint4*)(xin + (size_t)img * 8192 + i * 8);
        int pix = i >> 2, grp = i & 3;
        *(uint4*)&xs[(pix >> 4) + 2][(pix & 15) + 2][grp * 8] = val;
    }
    __syncthreads();

    const int lane = t & 63, wave = t >> 6;
    const int lo = lane & 15, hi = lane >> 4;

    v4f acc[2][2][2];                           // [rpi][yb][nt]
    #pragma unroll
    for (int a0 = 0; a0 < 2; ++a0)
        #pragma unroll
        for (int a1 = 0; a1 < 2; ++a1)
            #pragma unroll
            for (int a2 = 0; a2 < 2; ++a2)
                acc[a0][a1][a2] = (v4f){0.f, 0.f, 0.f, 0.f};

    for (int kx = 0; kx < 5; ++kx) {
        v8bf bf[5][2];
        #pragma unroll
        for (int ky = 0; ky < 5; ++ky) {
            bf[ky][0] = *(const v8bf*)(fb + ((ky * 5 + kx) * 2 + 0) * 512 + lane * 8);
            bf[ky][1] = *(const v8bf*)(fb + ((ky * 5 + kx) * 2 + 1) * 512 + lane * 8);
        }
        #pragma unroll
        for (int rpi = 0; rpi < 2; ++rpi) {
            const int rbase = (wave + rpi * 4) * 2;
            v8bf av[6];
            #pragma unroll
            for (int r = 0; r < 6; ++r)
                av[r] = *(const v8bf*)&xs[rbase + r][lo + kx][hi * 8];
            #pragma unroll
            for (int ky = 0; ky < 5; ++ky) {
                acc[rpi][0][0] = __builtin_amdgcn_mfma_f32_16x16x32_bf16(av[ky],     bf[ky][0], acc[rpi][0][0], 0, 0, 0);
                acc[rpi][0][1] = __builtin_amdgcn_mfma_f32_16x16x32_bf16(av[ky],     bf[ky][1], acc[rpi][0][1], 0, 0, 0);
                acc[rpi][1][0] = __builtin_amdgcn_mfma_f32_16x16x32_bf16(av[ky + 1], bf[ky][0], acc[rpi][1][0], 0, 0, 0);
                acc[rpi][1][1] = __builtin_amdgcn_mfma_f32_16x16x32_bf16(av[ky + 1], bf[ky][1], acc[rpi][1][1], 0, 0, 0);
            }
        }
    }

    #pragma unroll
    for (int rpi = 0; rpi < 2; ++rpi) {
        const int rp = wave + rpi * 4;
        #pragma unroll
        for (int nt = 0; nt < 2; ++nt) {
            const int oc = nt * 16 + lo;
            const float s = sc[oc], bb = bi[oc];
            float u0 = fmaxf(fmaf(acc[rpi][0][nt][0], s, bb), 0.f);
            float u1 = fmaxf(fmaf(acc[rpi][0][nt][1], s, bb), 0.f);
            float u2 = fmaxf(fmaf(acc[rpi][0][nt][2], s, bb), 0.f);
            float u3 = fmaxf(fmaf(acc[rpi][0][nt][3], s, bb), 0.f);
            float q0 = fmaxf(fmaf(acc[rpi][1][nt][0], s, bb), 0.f);
            float q1 = fmaxf(fmaf(acc[rpi][1][nt][1], s, bb), 0.f);
            float q2 = fmaxf(fmaf(acc[rpi][1][nt][2], s, bb), 0.f);
            float q3 = fmaxf(fmaf(acc[rpi][1][nt][3], s, bb), 0.f);
            float p0 = fminf(0.25f * (u0 + u1 + q0 + q1), 1.f);
            float p1 = fminf(0.25f * (u2 + u3 + q2 + q3), 1.f);
            size_t base = (size_t)img * 2048 + (rp * 8 + hi * 2) * 32 + oc;
            out[base]      = __float2bfloat16(p0);
            out[base + 32] = __float2bfloat16(p1);
        }
    }
}

// ---------------------------------------------------------------------------
// Block 3 (MFMA): conv 32->64 (5x5 pad2, 8x8) -> BN -> ReLU -> pool -> clip
// 2 images per block (B-frag L2 traffic halved). ic dim padded to 40.
// ---------------------------------------------------------------------------
__global__ __launch_bounds__(256, 2) void k_block3(
    const __hip_bfloat16* __restrict__ xin, const __hip_bfloat16* __restrict__ fb,
    const float* __restrict__ g, const float* __restrict__ b,
    const float* __restrict__ m, const float* __restrict__ v,
    float* __restrict__ out)
{
    __shared__ __hip_bfloat16 xs[2][12][12][40];   // 23 KB
    __shared__ float sc[64], bi[64];
    const int img0 = blockIdx.x * 2, t = threadIdx.x;

    for (int i = t; i < 1440; i += 256) ((uint4*)xs)[i] = make_uint4(0, 0, 0, 0);
    if (t < 64) {
        float s = g[t] * rsqrtf(v[t] + EPS);
        sc[t] = s; bi[t] = b[t] - m[t] * s;
    }
    __syncthreads();
    for (int i = t; i < 512; i += 256) {
        int im = i >> 8, j = i & 255;
        uint4 val = *(const uint4*)(xin + (size_t)(img0 + im) * 2048 + j * 8);
        int pix = j >> 2, grp = j & 3;
        *(uint4*)&xs[im][(pix >> 3) + 2][(pix & 7) + 2][grp * 8] = val;
    }
    __syncthreads();

    const int lane = t & 63, w = t >> 6;
    const int lo = lane & 15, hi = lane >> 4;
    const int ya = 2 * w + (lo >> 3), xa = lo & 7;

    v4f aA[4], aB[4];
    #pragma unroll
    for (int q = 0; q < 4; ++q) { aA[q] = (v4f){0.f,0.f,0.f,0.f}; aB[q] = (v4f){0.f,0.f,0.f,0.f}; }

    #pragma unroll
    for (int tap = 0; tap < 25; ++tap) {
        const int ky = tap / 5, kx = tap % 5;
        v8bf avA = *(const v8bf*)&xs[0][ya + ky][xa + kx][hi * 8];
        v8bf avB = *(const v8bf*)&xs[1][ya + ky][xa + kx][hi * 8];
        #pragma unroll
        for (int nt = 0; nt < 4; ++nt) {
            v8bf bfr = *(const v8bf*)(fb + (tap * 4 + nt) * 512 + lane * 8);
            aA[nt] = __builtin_amdgcn_mfma_f32_16x16x32_bf16(avA, bfr, aA[nt], 0, 0, 0);
            aB[nt] = __builtin_amdgcn_mfma_f32_16x16x32_bf16(avB, bfr, aB[nt], 0, 0, 0);
        }
    }

    const int xb = (hi & 1) * 2;
    #pragma unroll
    for (int im = 0; im < 2; ++im) {
        const int img = img0 + im;
        #pragma unroll
        for (int nt = 0; nt < 4; ++nt) {
            v4f ac = im == 0 ? aA[nt] : aB[nt];
            const int oc = nt * 16 + lo;
            const float s = sc[oc], bb = bi[oc];
            float v0 = fmaxf(fmaf(ac[0], s, bb), 0.f);
            float v1 = fmaxf(fmaf(ac[1], s, bb), 0.f);
            float v2 = fmaxf(fmaf(ac[2], s, bb), 0.f);
            float v3 = fmaxf(fmaf(ac[3], s, bb), 0.f);
            float s01 = v0 + v1, s23 = v2 + v3;
            float o01 = __shfl_xor(s01, 32);
            float o23 = __shfl_xor(s23, 32);
            float p0 = fminf(0.25f * (s01 + o01), 1.f);
            float p1 = fminf(0.25f * (s23 + o23), 1.f);
            if (hi < 2) {
                size_t base = (size_t)img * 1024 + oc * 16 + w * 4 + xb;
                out[base] = p0; out[base + 1] = p1;
            }
        }
    }
}

// ---------------------------------------------------------------------------
// Final: [1024,1024]x[1024,10] + BN1d affine. One wave per image.
// ---------------------------------------------------------------------------
__global__ __launch_bounds__(256) void k_final(
    const float* __restrict__ xin, const float* __restrict__ w,
    const float* __restrict__ g, const float* __restrict__ b,
    const float* __restrict__ m, const float* __restrict__ v,
    float* __restrict__ out)
{
    const int t = threadIdx.x, lane = t & 63, wv = t >> 6;
    const int img = blockIdx.x * 4 + wv;
    const float4* xp = (const float4*)(xin + (size_t)img * 1024) + lane * 4;
    float4 a0 = xp[0], a1 = xp[1], a2 = xp[2], a3 = xp[3];
    for (int oc = 0; oc < 10; ++oc) {
        const float4* wp = (const float4*)(w + oc * 1024) + lane * 4;
        float4 w0 = wp[0], w1 = wp[1], w2 = wp[2], w3 = wp[3];
        float acc0 = 0.f, acc1 = 0.f;
        acc0 = fmaf(a0.x, w0.x, acc0); acc1 = fmaf(a0.y, w0.y, acc1);
        acc0 = fmaf(a0.z, w0.z, acc0); acc1 = fmaf(a0.w, w0.w, acc1);
        acc0 = fmaf(a1.x, w1.x, acc0); acc1 = fmaf(a1.y, w1.y, acc1);
        acc0 = fmaf(a1.z, w1.z, acc0); acc1 = fmaf(a1.w, w1.w, acc1);
        acc0 = fmaf(a2.x, w2.x, acc0); acc1 = fmaf(a2.y, w2.y, acc1);
        acc0 = fmaf(a2.z, w2.z, acc0); acc1 = fmaf(a2.w, w2.w, acc1);
        acc0 = fmaf(a3.x, w3.x, acc0); acc1 = fmaf(a3.y, w3.y, acc1);
        acc0 = fmaf(a3.z, w3.z, acc0); acc1 = fmaf(a3.w, w3.w, acc1);
        float acc = acc0 + acc1;
        acc += __shfl_xor(acc, 1);
        acc += __shfl_xor(acc, 2);
        acc += __shfl_xor(acc, 4);
        acc += __shfl_xor(acc, 8);
        acc += __shfl_xor(acc, 16);
        acc += __shfl_xor(acc, 32);
        if (lane == 0) {
            float s = g[oc] * rsqrtf(v[oc] + EPS);
            out[img * 10 + oc] = acc * s + (b[oc] - m[oc] * s);
        }
    }
}

extern "C" void kernel_launch(void* const* d_in, const int* in_sizes, int n_in,
                              void* d_out, int out_size, void* d_ws, size_t ws_size,
                              hipStream_t stream) {
    const float* x  = (const float*)d_in[0];
    const float* w1 = (const float*)d_in[1];
    const float* g1 = (const float*)d_in[2];
    const float* b1 = (const float*)d_in[3];
    const float* m1 = (const float*)d_in[4];
    const float* v1 = (const float*)d_in[5];
    const float* w2 = (const float*)d_in[6];
    const float* g2 = (const float*)d_in[7];
    const float* b2 = (const float*)d_in[8];
    const float* m2 = (const float*)d_in[9];
    const float* v2 = (const float*)d_in[10];
    const float* w3 = (const float*)d_in[11];
    const float* g3 = (const float*)d_in[12];
    const float* b3 = (const float*)d_in[13];
    const float* m3 = (const float*)d_in[14];
    const float* v3 = (const float*)d_in[15];
    const float* w4 = (const float*)d_in[16];
    const float* g4 = (const float*)d_in[17];
    const float* b4 = (const float*)d_in[18];
    const float* m4 = (const float*)d_in[19];
    const float* v4 = (const float*)d_in[20];
    float* out = (float*)d_out;

    char* base = (char*)d_ws;
    __hip_bfloat16* buf1 = (__hip_bfloat16*)base;                 // 16.78 MB [1024][256][32]
    __hip_bfloat16* buf2 = (__hip_bfloat16*)(base + 16777216);    //  4.19 MB [1024][64][32]
    float*          buf3 = (float*)(base + 20971520);             //  4.19 MB [1024][64][16]
    __hip_bfloat16* fb1  = (__hip_bfloat16*)(base + 25165824);    //  10.24 KB
    __hip_bfloat16* fb2  = (__hip_bfloat16*)(base + 25176064);    //  51.2 KB
    __hip_bfloat16* fb3  = (__hip_bfloat16*)(base + 25227264);    // 102.4 KB

    k_wtrans<<<40, 256, 0, stream>>>(w1, w2, w3, fb1, fb2, fb3);
    k_block1<<<1024, 256, 0, stream>>>(x, fb1, g1, b1, m1, v1, buf1);
    k_block2<<<1024, 256, 0, stream>>>(buf1, fb2, g2, b2, m2, v2, buf2);
    k_block3<<<512, 256, 0, stream>>>(buf2, fb3, g3, b3, m3, v3, buf3);
    k_final<<<256, 256, 0, stream>>>(buf3, w4, g4, b4, m4, v4, out);
}

// Round 4
// 38.989 us; speedup vs baseline: 15.3847x; 1.5208x over previous
//
#include <hip/hip_runtime.h>
#include <hip/hip_bf16.h>

#define EPS 1e-5f

typedef __bf16 v8bf __attribute__((ext_vector_type(8)));
typedef __bf16 v4bf __attribute__((ext_vector_type(4)));
typedef float  v4f  __attribute__((ext_vector_type(4)));

// ---------------------------------------------------------------------------
// Weight transform: per-tap MFMA B-fragments (unchanged from R3).
// fb1: [ky(5)][nt(2)][lane(64)][8]  k=(dx,ic): dx=k>>2 (0..7), ic=k&3; zero pad
// fb2: [tap(25)][nt(2)][lane(64)][8]  k = ic (0..31)
// fb3: [tap(25)][nt(4)][lane(64)][8]  k = ic (0..31)
// B elem: lane l, reg j -> B[k=(l>>4)*8+j][n=l&15]
// ---------------------------------------------------------------------------
__global__ void k_wtrans(const float* __restrict__ w1, const float* __restrict__ w2,
                         const float* __restrict__ w3,
                         __hip_bfloat16* __restrict__ fb1, __hip_bfloat16* __restrict__ fb2,
                         __hip_bfloat16* __restrict__ fb3)
{
    int idx = blockIdx.x * 256 + threadIdx.x;
    if (idx < 640) {                               // fb1: 5*2*64
        int lane = idx & 63, fi = idx >> 6;        // fi = ky*2 + nt
        int ky = fi >> 1, nt = fi & 1;
        int oc = nt * 16 + (lane & 15), k0 = (lane >> 4) * 8;
        __hip_bfloat16* dst = fb1 + idx * 8;
        #pragma unroll
        for (int j = 0; j < 8; ++j) {
            int k = k0 + j, dx = k >> 2, ic = k & 3;
            float val = (dx < 5 && ic < 3) ? w1[oc * 75 + ic * 25 + ky * 5 + dx] : 0.f;
            dst[j] = __float2bfloat16(val);
        }
    } else if (idx < 640 + 3200) {                 // fb2: 25*2*64
        int k2 = idx - 640;
        int lane = k2 & 63, fi = k2 >> 6;          // fi = tap*2 + nt
        int tap = fi >> 1, nt = fi & 1;
        int oc = nt * 16 + (lane & 15), ic0 = (lane >> 4) * 8;
        __hip_bfloat16* dst = fb2 + k2 * 8;
        #pragma unroll
        for (int j = 0; j < 8; ++j)
            dst[j] = __float2bfloat16(w2[oc * 800 + (ic0 + j) * 25 + tap]);
    } else if (idx < 640 + 3200 + 6400) {          // fb3: 25*4*64
        int k3 = idx - 3840;
        int lane = k3 & 63, fi = k3 >> 6;          // fi = tap*4 + nt
        int tap = fi >> 2, nt = fi & 3;
        int oc = nt * 16 + (lane & 15), ic0 = (lane >> 4) * 8;
        __hip_bfloat16* dst = fb3 + k3 * 8;
        #pragma unroll
        for (int j = 0; j < 8; ++j)
            dst[j] = __float2bfloat16(w3[oc * 800 + (ic0 + j) * 25 + tap]);
    }
}

// ---------------------------------------------------------------------------
// Fused whole-network kernel: one block = one image, all layers in LDS.
// LDS pool (43840 B, phase-aliased):
//   xs2 [20][20][40] bf16 @ 0      (32000 B)  conv1-out / conv2-in (padded)
//   xs1 [37][40][4]  bf16 @ 32000  (11840 B)  conv1-in staging
//   xs3 [12][12][40] bf16 @ 32000  (11520 B)  conv2-out / conv3-in (overwrites xs1)
//   fin [1024]       f32  @ 0      ( 4096 B)  conv3-out / fc-in (overwrites xs2)
// ---------------------------------------------------------------------------
__global__ __launch_bounds__(256, 3) void k_fused(
    const float* __restrict__ x,
    const __hip_bfloat16* __restrict__ fb1,
    const __hip_bfloat16* __restrict__ fb2,
    const __hip_bfloat16* __restrict__ fb3,
    const float* __restrict__ w4,
    const float* __restrict__ g1, const float* __restrict__ b1,
    const float* __restrict__ m1, const float* __restrict__ v1,
    const float* __restrict__ g2, const float* __restrict__ b2,
    const float* __restrict__ m2, const float* __restrict__ v2,
    const float* __restrict__ g3, const float* __restrict__ b3,
    const float* __restrict__ m3, const float* __restrict__ v3,
    const float* __restrict__ g4, const float* __restrict__ b4,
    const float* __restrict__ m4, const float* __restrict__ v4,
    float* __restrict__ out)
{
    __shared__ __align__(16) unsigned char pool[43840];
    __shared__ float sc1[32], bi1[32], sc2[32], bi2[32], sc3[64], bi3[64];

    __hip_bfloat16 (*xs2)[20][40] = (__hip_bfloat16(*)[20][40])pool;
    __hip_bfloat16 (*xs1)[40][4]  = (__hip_bfloat16(*)[40][4])(pool + 32000);
    __hip_bfloat16 (*xs3)[12][40] = (__hip_bfloat16(*)[12][40])(pool + 32000);
    float* fin = (float*)pool;

    const int img = blockIdx.x, t = threadIdx.x;
    const int lane = t & 63, wave = t >> 6;
    const int lo = lane & 15, hi = lane >> 4;

    // ---- init: zero pool, build BN affine consts ----
    for (int i = t; i < 2740; i += 256) ((uint4*)pool)[i] = make_uint4(0, 0, 0, 0);
    if (t < 32) {
        float s = g1[t] * rsqrtf(v1[t] + EPS); sc1[t] = s; bi1[t] = b1[t] - m1[t] * s;
        float u = g2[t] * rsqrtf(v2[t] + EPS); sc2[t] = u; bi2[t] = b2[t] - m2[t] * u;
    }
    if (t < 64) {
        float s = g3[t] * rsqrtf(v3[t] + EPS); sc3[t] = s; bi3[t] = b3[t] - m3[t] * s;
    }
    __syncthreads();

    // ---- phase 0: stage input image -> xs1 (bf16, [y][x][ic] interior) ----
    #pragma unroll
    for (int it = 0; it < 3; ++it) {
        int i = t + it * 256;                  // 768 float4 total
        float4 val = *(const float4*)(x + (size_t)img * 3072 + i * 4);
        int ic = i >> 8, rem = i & 255;
        int y = rem >> 3, xx = (rem & 7) * 4;
        xs1[y + 2][xx + 2][ic] = __float2bfloat16(val.x);
        xs1[y + 2][xx + 3][ic] = __float2bfloat16(val.y);
        xs1[y + 2][xx + 4][ic] = __float2bfloat16(val.z);
        xs1[y + 2][xx + 5][ic] = __float2bfloat16(val.w);
    }
    __syncthreads();

    // ---- phase 1: conv1 (3->32) MFMA, K=(dx,ic) packing -> xs2 interior ----
    {
        v8bf bw[5][2];
        #pragma unroll
        for (int ky = 0; ky < 5; ++ky)
            #pragma unroll
            for (int nt = 0; nt < 2; ++nt)
                bw[ky][nt] = *(const v8bf*)(fb1 + ((ky * 2 + nt) * 64 + lane) * 8);

        #pragma unroll
        for (int pi = 0; pi < 4; ++pi) {
            const int pr = wave + pi * 4;      // pooled row 0..15
            const int y0 = 2 * pr;
            v4f acc[2][2][2];                  // [yb][xh][nt]
            #pragma unroll
            for (int a0 = 0; a0 < 2; ++a0)
                #pragma unroll
                for (int a1 = 0; a1 < 2; ++a1)
                    #pragma unroll
                    for (int a2 = 0; a2 < 2; ++a2)
                        acc[a0][a1][a2] = (v4f){0.f, 0.f, 0.f, 0.f};

            #pragma unroll
            for (int xh = 0; xh < 2; ++xh) {
                const int xx = xh * 16 + lo + hi * 2;
                v8bf av[6];
                #pragma unroll
                for (int r = 0; r < 6; ++r) {
                    v4bf lo4 = *(const v4bf*)&xs1[y0 + r][xx][0];
                    v4bf hi4 = *(const v4bf*)&xs1[y0 + r][xx + 1][0];
                    av[r] = __builtin_shufflevector(lo4, hi4, 0, 1, 2, 3, 4, 5, 6, 7);
                }
                #pragma unroll
                for (int ky = 0; ky < 5; ++ky) {
                    acc[0][xh][0] = __builtin_amdgcn_mfma_f32_16x16x32_bf16(av[ky],     bw[ky][0], acc[0][xh][0], 0, 0, 0);
                    acc[0][xh][1] = __builtin_amdgcn_mfma_f32_16x16x32_bf16(av[ky],     bw[ky][1], acc[0][xh][1], 0, 0, 0);
                    acc[1][xh][0] = __builtin_amdgcn_mfma_f32_16x16x32_bf16(av[ky + 1], bw[ky][0], acc[1][xh][0], 0, 0, 0);
                    acc[1][xh][1] = __builtin_amdgcn_mfma_f32_16x16x32_bf16(av[ky + 1], bw[ky][1], acc[1][xh][1], 0, 0, 0);
                }
            }
            // epilogue -> xs2[pr+2][px+2][oc]
            #pragma unroll
            for (int xh = 0; xh < 2; ++xh)
                #pragma unroll
                for (int nt = 0; nt < 2; ++nt) {
                    const int oc = nt * 16 + lo;
                    const float s = sc1[oc], bb = bi1[oc];
                    float u0 = fmaxf(fmaf(acc[0][xh][nt][0], s, bb), 0.f);
                    float u1 = fmaxf(fmaf(acc[0][xh][nt][1], s, bb), 0.f);
                    float u2 = fmaxf(fmaf(acc[0][xh][nt][2], s, bb), 0.f);
                    float u3 = fmaxf(fmaf(acc[0][xh][nt][3], s, bb), 0.f);
                    float q0 = fmaxf(fmaf(acc[1][xh][nt][0], s, bb), 0.f);
                    float q1 = fmaxf(fmaf(acc[1][xh][nt][1], s, bb), 0.f);
                    float q2 = fmaxf(fmaf(acc[1][xh][nt][2], s, bb), 0.f);
                    float q3 = fmaxf(fmaf(acc[1][xh][nt][3], s, bb), 0.f);
                    float p0 = fminf(0.25f * (u0 + u1 + q0 + q1), 1.f);
                    float p1 = fminf(0.25f * (u2 + u3 + q2 + q3), 1.f);
                    const int px = xh * 8 + hi * 2;
                    xs2[pr + 2][px + 2][oc] = __float2bfloat16(p0);
                    xs2[pr + 2][px + 3][oc] = __float2bfloat16(p1);
                }
        }
    }
    __syncthreads();

    // ---- zero xs3 (overwrites dead xs1) ----
    {
        uint4* p3 = (uint4*)(pool + 32000);
        for (int i = t; i < 720; i += 256) p3[i] = make_uint4(0, 0, 0, 0);
    }
    __syncthreads();

    // ---- phase 2: conv2 (32->32) MFMA, nt-split waves -> xs3 interior ----
    {
        const int nt = wave & 1, wgrp = wave >> 1;
        v4f acc[4][2];                          // [rpi][yb]
        #pragma unroll
        for (int a0 = 0; a0 < 4; ++a0)
            #pragma unroll
            for (int a1 = 0; a1 < 2; ++a1)
                acc[a0][a1] = (v4f){0.f, 0.f, 0.f, 0.f};

        for (int kx = 0; kx < 5; ++kx) {
            v8bf bf[5];
            #pragma unroll
            for (int ky = 0; ky < 5; ++ky)
                bf[ky] = *(const v8bf*)(fb2 + ((ky * 5 + kx) * 2 + nt) * 512 + lane * 8);
            #pragma unroll
            for (int rpi = 0; rpi < 4; ++rpi) {
                const int rbase = (wgrp * 4 + rpi) * 2;
                v8bf av[6];
                #pragma unroll
                for (int r = 0; r < 6; ++r)
                    av[r] = *(const v8bf*)&xs2[rbase + r][lo + kx][hi * 8];
                #pragma unroll
                for (int ky = 0; ky < 5; ++ky) {
                    acc[rpi][0] = __builtin_amdgcn_mfma_f32_16x16x32_bf16(av[ky],     bf[ky], acc[rpi][0], 0, 0, 0);
                    acc[rpi][1] = __builtin_amdgcn_mfma_f32_16x16x32_bf16(av[ky + 1], bf[ky], acc[rpi][1], 0, 0, 0);
                }
            }
        }
        const int oc = nt * 16 + lo;
        const float s = sc2[oc], bb = bi2[oc];
        #pragma unroll
        for (int rpi = 0; rpi < 4; ++rpi) {
            const int rp = wgrp * 4 + rpi;
            float u0 = fmaxf(fmaf(acc[rpi][0][0], s, bb), 0.f);
            float u1 = fmaxf(fmaf(acc[rpi][0][1], s, bb), 0.f);
            float u2 = fmaxf(fmaf(acc[rpi][0][2], s, bb), 0.f);
            float u3 = fmaxf(fmaf(acc[rpi][0][3], s, bb), 0.f);
            float q0 = fmaxf(fmaf(acc[rpi][1][0], s, bb), 0.f);
            float q1 = fmaxf(fmaf(acc[rpi][1][1], s, bb), 0.f);
            float q2 = fmaxf(fmaf(acc[rpi][1][2], s, bb), 0.f);
            float q3 = fmaxf(fmaf(acc[rpi][1][3], s, bb), 0.f);
            float p0 = fminf(0.25f * (u0 + u1 + q0 + q1), 1.f);
            float p1 = fminf(0.25f * (u2 + u3 + q2 + q3), 1.f);
            xs3[rp + 2][hi * 2 + 2][oc] = __float2bfloat16(p0);
            xs3[rp + 2][hi * 2 + 3][oc] = __float2bfloat16(p1);
        }
    }
    __syncthreads();

    // ---- phase 3: conv3 (32->64) MFMA, wave = nt, 4 M-tiles each -> fin ----
    {
        const int nt = wave;
        const int oc = nt * 16 + lo;
        const int ya0 = lo >> 3, xa = lo & 7;
        v4f acc[4];
        #pragma unroll
        for (int q = 0; q < 4; ++q) acc[q] = (v4f){0.f, 0.f, 0.f, 0.f};

        #pragma unroll
        for (int tap = 0; tap < 25; ++tap) {
            const int ky = tap / 5, kx = tap % 5;
            v8bf bfr = *(const v8bf*)(fb3 + (tap * 4 + nt) * 512 + lane * 8);
            #pragma unroll
            for (int mt = 0; mt < 4; ++mt) {
                v8bf av = *(const v8bf*)&xs3[2 * mt + ya0 + ky][xa + kx][hi * 8];
                acc[mt] = __builtin_amdgcn_mfma_f32_16x16x32_bf16(av, bfr, acc[mt], 0, 0, 0);
            }
        }
        const float s = sc3[oc], bb = bi3[oc];
        const int xb = (hi & 1) * 2;
        #pragma unroll
        for (int mt = 0; mt < 4; ++mt) {
            float v0 = fmaxf(fmaf(acc[mt][0], s, bb), 0.f);
            float v1 = fmaxf(fmaf(acc[mt][1], s, bb), 0.f);
            float v2 = fmaxf(fmaf(acc[mt][2], s, bb), 0.f);
            float v3 = fmaxf(fmaf(acc[mt][3], s, bb), 0.f);
            float s01 = v0 + v1, s23 = v2 + v3;
            float o01 = __shfl_xor(s01, 32);
            float o23 = __shfl_xor(s23, 32);
            float p0 = fminf(0.25f * (s01 + o01), 1.f);
            float p1 = fminf(0.25f * (s23 + o23), 1.f);
            if (hi < 2) {
                fin[oc * 16 + mt * 4 + xb]     = p0;
                fin[oc * 16 + mt * 4 + xb + 1] = p1;
            }
        }
    }
    __syncthreads();

    // ---- phase 4: FC 1024->10 + BN1d, wave handles oc = wave, wave+4, ... ----
    {
        for (int oc = wave; oc < 10; oc += 4) {
            const float4* wp = (const float4*)(w4 + oc * 1024);
            const float4* fp = (const float4*)fin;
            float acc0 = 0.f, acc1 = 0.f;
            #pragma unroll
            for (int ch = 0; ch < 4; ++ch) {
                float4 a = fp[ch * 64 + lane];
                float4 w = wp[ch * 64 + lane];
                acc0 = fmaf(a.x, w.x, acc0); acc1 = fmaf(a.y, w.y, acc1);
                acc0 = fmaf(a.z, w.z, acc0); acc1 = fmaf(a.w, w.w, acc1);
            }
            float acc = acc0 + acc1;
            acc += __shfl_xor(acc, 1);
            acc += __shfl_xor(acc, 2);
            acc += __shfl_xor(acc, 4);
            acc += __shfl_xor(acc, 8);
            acc += __shfl_xor(acc, 16);
            acc += __shfl_xor(acc, 32);
            if (lane == 0) {
                float s = g4[oc] * rsqrtf(v4[oc] + EPS);
                out[img * 10 + oc] = acc * s + (b4[oc] - m4[oc] * s);
            }
        }
    }
}

extern "C" void kernel_launch(void* const* d_in, const int* in_sizes, int n_in,
                              void* d_out, int out_size, void* d_ws, size_t ws_size,
                              hipStream_t stream) {
    const float* x  = (const float*)d_in[0];
    const float* w1 = (const float*)d_in[1];
    const float* g1 = (const float*)d_in[2];
    const float* b1 = (const float*)d_in[3];
    const float* m1 = (const float*)d_in[4];
    const float* v1 = (const float*)d_in[5];
    const float* w2 = (const float*)d_in[6];
    const float* g2 = (const float*)d_in[7];
    const float* b2 = (const float*)d_in[8];
    const float* m2 = (const float*)d_in[9];
    const float* v2 = (const float*)d_in[10];
    const float* w3 = (const float*)d_in[11];
    const float* g3 = (const float*)d_in[12];
    const float* b3 = (const float*)d_in[13];
    const float* m3 = (const float*)d_in[14];
    const float* v3 = (const float*)d_in[15];
    const float* w4 = (const float*)d_in[16];
    const float* g4 = (const float*)d_in[17];
    const float* b4 = (const float*)d_in[18];
    const float* m4 = (const float*)d_in[19];
    const float* v4 = (const float*)d_in[20];
    float* out = (float*)d_out;

    char* base = (char*)d_ws;
    __hip_bfloat16* fb1 = (__hip_bfloat16*)base;             // 10.24 KB (pad to 16K)
    __hip_bfloat16* fb2 = (__hip_bfloat16*)(base + 16384);   // 51.2 KB
    __hip_bfloat16* fb3 = (__hip_bfloat16*)(base + 67584);   // 102.4 KB

    k_wtrans<<<40, 256, 0, stream>>>(w1, w2, w3, fb1, fb2, fb3);
    k_fused<<<1024, 256, 0, stream>>>(x, fb1, fb2, fb3, w4,
                                      g1, b1, m1, v1, g2, b2, m2, v2,
                                      g3, b3, m3, v3, g4, b4, m4, v4, out);
}